// Round 5
// baseline (85.334 us; speedup 1.0000x reference)
//
#include <hip/hip_runtime.h>

typedef __bf16 bf16x8 __attribute__((ext_vector_type(8)));
typedef float f32x16 __attribute__((ext_vector_type(16)));

#define N_EMB 4096
#define DIM 64
#define NCHUNK 128            // 4096 entries / 32 per chunk
#define CH_STRIDE 5120        // packed chunk: 4KB A-frags + 1KB wn-as-A5 block
#define RPB 128               // rows per block = 4 waves x 32
#define NWAVES 4

// ---------------- prep: packed stream Sp, one 5120B record per chunk ----------------
// bytes [0,4096):  A-frags, A-layout (validated rounds 2-4):
//   lane l of 32x32x16 holds A[m=l%32][k=8*(l/32)+e] ->
//   Sp[g*5120 + s*1024 + l*16 + 2e] = bf16(-2 * W[g*32 + l%32][s*16 + (l/32)*8 + e])
// bytes [4096,5120): A5 block: lane l<32: {bf16(||W[g*32+l]||^2), 0 x7}; lanes>=32: 0
//   (with B5 = e_0, MFMA adds wn(m) to every output column -> full distance in acc)
__global__ void prep_kernel(const float* __restrict__ w, char* __restrict__ Sp) {
    int id = blockIdx.x * blockDim.x + threadIdx.x;   // 8192 = 128 chunks * 64 lanes
    if (id >= NCHUNK * 64) return;
    int g = id >> 6, l = id & 63;
    int hi = l >> 5;
    const float* wr = w + (size_t)((g << 5) + (l & 31)) * DIM + hi * 8;
    char* base = Sp + (size_t)g * CH_STRIDE;
    float ss = 0.f;
#pragma unroll
    for (int s = 0; s < 4; ++s) {
        const float4* p = (const float4*)(wr + s * 16);
        float4 v0 = p[0], v1 = p[1];
        ss += v0.x*v0.x + v0.y*v0.y + v0.z*v0.z + v0.w*v0.w;
        ss += v1.x*v1.x + v1.y*v1.y + v1.z*v1.z + v1.w*v1.w;
        bf16x8 o;
        o[0]=(__bf16)(-2.f*v0.x); o[1]=(__bf16)(-2.f*v0.y);
        o[2]=(__bf16)(-2.f*v0.z); o[3]=(__bf16)(-2.f*v0.w);
        o[4]=(__bf16)(-2.f*v1.x); o[5]=(__bf16)(-2.f*v1.y);
        o[6]=(__bf16)(-2.f*v1.z); o[7]=(__bf16)(-2.f*v1.w);
        *(bf16x8*)(base + s * 1024 + l * 16) = o;
    }
    ss += __shfl_xor(ss, 32, 64);   // full-row norm on lanes 0-31 (row = g*32 + l)
    bf16x8 a5 = {};
    if (l < 32) a5[0] = (__bf16)ss;
    *(bf16x8*)(base + 4096 + l * 16) = a5;
}

// ---------------- main ----------------
__device__ __forceinline__ void gload_lds16(const void* g, void* l) {
    __builtin_amdgcn_global_load_lds(
        (const __attribute__((address_space(1))) unsigned int*)g,
        (__attribute__((address_space(3))) unsigned int*)l, 16, 0, 0);
}

__global__ void __launch_bounds__(256) vq_main(
    const float* __restrict__ x, const float* __restrict__ w,
    const char* __restrict__ Sp,
    float* __restrict__ qout, float* __restrict__ lout, int nrows) {
    __shared__ char lds[2][CH_STRIDE];   // 10 KB double buffer
    __shared__ int  sidx[RPB];

    const int tid  = threadIdx.x;
    const int wv   = tid >> 6;
    const int lane = tid & 63;
    const int li   = lane & 31;
    const int hi   = lane >> 5;
    const int rowBase = blockIdx.x * RPB;
    const int rot = (blockIdx.x * 13) & (NCHUNK - 1);   // desync chunk order

    // x B-frag: lane holds col n = li (row rowBase+wv*32+li), k = 8*hi + e
    bf16x8 xb[4];
    {
        int row = rowBase + wv * 32 + li;
        if (row >= nrows) row = nrows - 1;
#pragma unroll
        for (int s = 0; s < 4; ++s) {
            const float4* p = (const float4*)(x + (size_t)row * DIM + s * 16 + hi * 8);
            float4 v0 = p[0], v1 = p[1];
            bf16x8 v;
            v[0]=(__bf16)v0.x; v[1]=(__bf16)v0.y; v[2]=(__bf16)v0.z; v[3]=(__bf16)v0.w;
            v[4]=(__bf16)v1.x; v[5]=(__bf16)v1.y; v[6]=(__bf16)v1.z; v[7]=(__bf16)v1.w;
            xb[s] = v;
        }
    }
    bf16x8 xone = {};                 // B5 = e_0: k=0 -> hi==0, e==0
    if (hi == 0) xone[0] = (__bf16)1.0f;
    f32x16 zacc = {};                 // zero C operand (loop-invariant)

    float pb[16];
#pragma unroll
    for (int r = 0; r < 16; ++r) pb[r] = 3.4e38f;

    // ---- staging: 256 threads x 16B cover the 4KB A region; wave 0 covers A5 ----
    #define STAGE(cc) do { \
        int eff_ = ((cc) + rot) & (NCHUNK - 1); \
        const char* src_ = Sp + (size_t)eff_ * CH_STRIDE; \
        char* db_ = (char*)lds[(cc) & 1]; \
        gload_lds16(src_ + tid * 16, db_ + (wv << 10)); \
        if (wv == 0) gload_lds16(src_ + 4096 + lane * 16, db_ + 4096); \
    } while (0)

    STAGE(0); STAGE(1);
    asm volatile("s_waitcnt vmcnt(0)" ::: "memory");
    __builtin_amdgcn_s_barrier();

    for (int c = 0; c < NCHUNK; ++c) {
        const bf16x8* bv = (const bf16x8*)lds[c & 1];
        bf16x8 a0 = bv[lane];
        bf16x8 a1 = bv[64 + lane];
        bf16x8 a2 = bv[128 + lane];
        bf16x8 a3 = bv[192 + lane];
        bf16x8 a5 = bv[256 + lane];
        asm volatile("s_waitcnt lgkmcnt(0)" ::: "memory");  // regs loaded; buf free
        __builtin_amdgcn_s_barrier();                        // all waves done reading
        if (c + 2 < NCHUNK) STAGE(c + 2);                    // refill buf[c&1]

        // distances: two independent MFMA chains (3 + 2) then add
        f32x16 accA = __builtin_amdgcn_mfma_f32_32x32x16_bf16(a5, xone, zacc, 0, 0, 0);
        accA = __builtin_amdgcn_mfma_f32_32x32x16_bf16(a0, xb[0], accA, 0, 0, 0);
        accA = __builtin_amdgcn_mfma_f32_32x32x16_bf16(a1, xb[1], accA, 0, 0, 0);
        f32x16 accB = __builtin_amdgcn_mfma_f32_32x32x16_bf16(a2, xb[2], zacc, 0, 0, 0);
        accB = __builtin_amdgcn_mfma_f32_32x32x16_bf16(a3, xb[3], accB, 0, 0, 0);

        const uint32_t ctag = (uint32_t)((c + rot) & (NCHUNK - 1));
#pragma unroll
        for (int r = 0; r < 16; ++r) {
            float d = accA[r] + accB[r];
            uint32_t t = (__builtin_bit_cast(uint32_t, d) & 0xFFFFFF80u) | ctag;
            pb[r] = fminf(pb[r], __builtin_bit_cast(float, t));
        }

        // counted waits (T4): stage(c+1) must be landed; stage(c+2) stays in flight
        if (c + 2 < NCHUNK) {
            if (wv == 0) asm volatile("s_waitcnt vmcnt(2)" ::: "memory");
            else         asm volatile("s_waitcnt vmcnt(1)" ::: "memory");
        } else {
            asm volatile("s_waitcnt vmcnt(0)" ::: "memory");
        }
        __builtin_amdgcn_s_barrier();
    }

    // merge 16 chains -> entry id; hi-half merge; publish per-row index
    {
        float bvv = pb[0];
        int   br  = 0;
#pragma unroll
        for (int r = 1; r < 16; ++r) {
            bool t = pb[r] < bvv;
            bvv = t ? pb[r] : bvv;
            br  = t ? r : br;
        }
        uint32_t bits = __builtin_bit_cast(uint32_t, bvv);
        uint32_t ctag = bits & 127u;
        uint32_t entry = (ctag << 5) + (uint32_t)((br & 3) + ((br >> 2) << 3)) +
                         ((uint32_t)hi << 2);
        float pv = __builtin_bit_cast(float, (bits & 0xFFFFF000u) | entry);
        float ov = __shfl_xor(pv, 32, 64);
        pv = fminf(pv, ov);
        if (lane < 32) sidx[wv * 32 + li] = (int)(__builtin_bit_cast(uint32_t, pv) & 0xFFFu);
    }
    __syncthreads();

    // fused epilogue: gather exact f32 codebook row, write quantized + loss
    {
        int rl = tid >> 1, part = tid & 1;    // 256 threads = 128 rows x 2 halves
        int row = rowBase + rl;
        if (row < nrows) {
            int e = sidx[rl];
            const float4* wr = (const float4*)(w + (size_t)e * DIM + part * 32);
            const float4* xr = (const float4*)(x + (size_t)row * DIM + part * 32);
            float4* qo = (float4*)(qout + (size_t)row * DIM + part * 32);
            float4* lo = (float4*)(lout + (size_t)row * DIM + part * 32);
#pragma unroll
            for (int j = 0; j < 8; ++j) {
                float4 q = wr[j], xv = xr[j], df, qv, lv;
                df.x = q.x - xv.x; df.y = q.y - xv.y; df.z = q.z - xv.z; df.w = q.w - xv.w;
                qv.x = xv.x + df.x; qv.y = xv.y + df.y; qv.z = xv.z + df.z; qv.w = xv.w + df.w;
                float sx = df.x*df.x, sy = df.y*df.y, sz = df.z*df.z, sw = df.w*df.w;
                lv.x = sx + 0.25f*sx; lv.y = sy + 0.25f*sy;
                lv.z = sz + 0.25f*sz; lv.w = sw + 0.25f*sw;
                qo[j] = qv;
                lo[j] = lv;
            }
        }
    }
}

extern "C" void kernel_launch(void* const* d_in, const int* in_sizes, int n_in,
                              void* d_out, int out_size, void* d_ws, size_t ws_size,
                              hipStream_t stream) {
    const float* x = (const float*)d_in[0];   // [8,4096,64] f32
    const float* w = (const float*)d_in[1];   // [4096,64] f32
    const int nrows = in_sizes[0] / DIM;      // 32768
    float* qout = (float*)d_out;
    float* lout = (float*)d_out + (size_t)nrows * DIM;

    char* Sp = (char*)d_ws;                   // packed stream, 128 * 5120 = 640 KB

    prep_kernel<<<(NCHUNK * 64 + 255) / 256, 256, 0, stream>>>(w, Sp);

    int nb = (nrows + RPB - 1) / RPB;         // 256 blocks, 4 waves each
    vq_main<<<nb, 256, 0, stream>>>(x, w, Sp, qout, lout, nrows);
}